// Round 1
// baseline (452.302 us; speedup 1.0000x reference)
//
#include <hip/hip_runtime.h>
#include <hip/hip_bf16.h>
#include <math.h>

// Problem constants (from reference setup_inputs):
//   x: [128, 8192] f32, scale_weights: [32] f32, out: [128, 32] f32
#define NT     8192              // time length
#define NS     32                // scales
#define PAD    128               // Lmax/2 zero pad each side
#define XBUF   (NT + 2*PAD)      // 8448 floats = 33 KB
#define BLOCK  256
#define ROUT   8                 // consecutive outputs per thread per pass
#define TPASS  (BLOCK*ROUT)      // 2048 outputs per pass
#define NPASS  (NT/TPASS)        // 4

// coef[t] = sum_{u=0}^{L-1} W[u] * X[t + 128 - 4s + u]
//   X = zero-padded x row, W[u] = wavelet (symmetric; reversed == same)
//   energy[b,s] = mean_t coef^2 ; out = energy * softmax(sw)

__global__ __launch_bounds__(BLOCK)
void cwt_energy_kernel(const float* __restrict__ x,
                       const float* __restrict__ sw,
                       float* __restrict__ out)
{
    __shared__ float X[XBUF];
    __shared__ float W[256];
    __shared__ float red[BLOCK/64];

    const int tid   = threadIdx.x;
    const int bid   = blockIdx.x;
    const int sidx  = bid & (NS - 1);   // 0..31 (consecutive blocks -> different scales: balance)
    const int batch = bid >> 5;
    const int s     = sidx + 1;
    const int L     = 8 * s;            // wavelet length (<= 256)

    // ---- stage x row into LDS, zero-padded ----
    const float4* xv = reinterpret_cast<const float4*>(x + (size_t)batch * NT);
    float4*       Xv = reinterpret_cast<float4*>(X + PAD);
#pragma unroll
    for (int k = 0; k < NT / 4 / BLOCK; ++k)       // 8 iterations, coalesced
        Xv[tid + k * BLOCK] = xv[tid + k * BLOCK];
    if (tid < PAD) { X[tid] = 0.f; X[PAD + NT + tid] = 0.f; }

    // ---- wavelet for this scale (even function: reversed == forward) ----
    if (tid < L) {
        // tau = linspace(-4, 4, L)[tid];  w = exp(-tau^2/2)*cos(5 tau)/sqrt(s)
        float tau = fmaf(8.0f / (float)(L - 1), (float)tid, -4.0f);
        float g   = expf(-0.5f * tau * tau) * cosf(5.0f * tau);
        W[tid] = g / sqrtf((float)s);
    }

    // ---- softmax weight for this scale (redundant per thread, cheap) ----
    float mx = -1e30f;
    for (int i = 0; i < NS; ++i) mx = fmaxf(mx, sw[i]);
    float ssum = 0.f;
    for (int i = 0; i < NS; ++i) ssum += expf(sw[i] - mx);
    const float wsoft = expf(sw[sidx] - mx) / ssum;

    __syncthreads();

    const int shift = PAD - 4 * s;      // multiple of 4 -> float4-aligned windows
    float e = 0.f;

    for (int pass = 0; pass < NPASS; ++pass) {
        const float*  Xb  = X + pass * TPASS + tid * ROUT + shift;
        const float4* Xb4 = reinterpret_cast<const float4*>(Xb);

        float acc[ROUT];
#pragma unroll
        for (int r = 0; r < ROUT; ++r) acc[r] = 0.f;

        float xw[16];
        {
            float4 a0 = Xb4[0], a1 = Xb4[1];
            xw[0]=a0.x; xw[1]=a0.y; xw[2]=a0.z; xw[3]=a0.w;
            xw[4]=a1.x; xw[5]=a1.y; xw[6]=a1.z; xw[7]=a1.w;
        }

        for (int u0 = 0; u0 < L; u0 += 8) {
            float4 b0 = Xb4[u0/4 + 2];
            float4 b1 = Xb4[u0/4 + 3];
            xw[8]=b0.x;  xw[9]=b0.y;  xw[10]=b0.z; xw[11]=b0.w;
            xw[12]=b1.x; xw[13]=b1.y; xw[14]=b1.z; xw[15]=b1.w;

            const float4 w0 = *reinterpret_cast<const float4*>(&W[u0]);
            const float4 w1 = *reinterpret_cast<const float4*>(&W[u0 + 4]);
            float wreg[8] = {w0.x, w0.y, w0.z, w0.w, w1.x, w1.y, w1.z, w1.w};

#pragma unroll
            for (int j = 0; j < 8; ++j)
#pragma unroll
                for (int r = 0; r < ROUT; ++r)
                    acc[r] = fmaf(wreg[j], xw[j + r], acc[r]);

#pragma unroll
            for (int k = 0; k < 8; ++k) xw[k] = xw[k + 8];
        }

#pragma unroll
        for (int r = 0; r < ROUT; ++r) e = fmaf(acc[r], acc[r], e);
    }

    // ---- block reduction of sum(coef^2) ----
#pragma unroll
    for (int off = 32; off > 0; off >>= 1) e += __shfl_down(e, off);
    if ((tid & 63) == 0) red[tid >> 6] = e;
    __syncthreads();
    if (tid == 0) {
        float tot = red[0] + red[1] + red[2] + red[3];
        out[batch * NS + sidx] = tot * (1.0f / (float)NT) * wsoft;
    }
}

extern "C" void kernel_launch(void* const* d_in, const int* in_sizes, int n_in,
                              void* d_out, int out_size, void* d_ws, size_t ws_size,
                              hipStream_t stream) {
    const float* x  = (const float*)d_in[0];
    const float* sw = (const float*)d_in[1];
    float* out = (float*)d_out;
    const int batch = in_sizes[0] / NT;   // 128
    hipLaunchKernelGGL(cwt_energy_kernel, dim3(batch * NS), dim3(BLOCK), 0, stream,
                       x, sw, out);
}

// Round 2
// 147.522 us; speedup vs baseline: 3.0660x; 3.0660x over previous
//
#include <hip/hip_runtime.h>
#include <hip/hip_bf16.h>
#include <math.h>

// x: [128, 8192] f32, scale_weights: [32] f32, out: [128, 32] f32
#define NT    8192
#define NS    32
#define PADF  128                  // left zero pad (floats); Lmax/2
#define XF4   2120                 // float4 slots in X buffer (8480 floats)
#define BLOCK 256
#define G     8                    // outputs per thread per pass
#define TPASS (BLOCK*G)            // 2048
#define NPASS (NT/TPASS)           // 4

// coef[t] = sum_{u=0}^{L-1} W[u] * X[t + 128 - 4s + u], X zero-padded
// energy[b,s] = mean_t coef^2 ; out = energy * softmax(sw)

__device__ __forceinline__ int swz(int f4) { return f4 ^ ((f4 >> 4) & 7); }

__global__ __launch_bounds__(BLOCK)
void cwt_energy_kernel(const float* __restrict__ x,
                       const float* __restrict__ sw,
                       float* __restrict__ out)
{
    __shared__ float4 X4[XF4];     // swizzled, padded x row
    __shared__ float  W[256];      // wavelet, zero-padded to 256 taps
    __shared__ float  red[BLOCK/64];

    const int tid   = threadIdx.x;
    const int bid   = blockIdx.x;
    const int batch = bid >> 5;                  // 0..127
    const int sidx  = (bid + batch) & (NS - 1);  // scrambled: CU residency cycles scales
    const int s     = sidx + 1;
    const int L     = 8 * s;                     // true wavelet length
    const int nc2   = (L + 15) >> 4;             // 16-tap iterations (W zero-padded)

    // ---- stage x row into LDS (swizzled), zero-padded ----
    const float4* xg = reinterpret_cast<const float4*>(x + (size_t)batch * NT);
#pragma unroll
    for (int k = 0; k < NT / 4 / BLOCK; ++k)     // 8 iters, coalesced
        X4[swz(32 + tid + k * BLOCK)] = xg[tid + k * BLOCK];
    if (tid < 32)  X4[swz(tid)]        = make_float4(0.f, 0.f, 0.f, 0.f);
    if (tid < 40)  X4[swz(2080 + tid)] = make_float4(0.f, 0.f, 0.f, 0.f);

    // ---- wavelet for this scale (symmetric: reversed == forward), zero pad ----
    {
        float val = 0.f;
        if (tid < L) {
            float tau = fmaf(8.0f / (float)(L - 1), (float)tid, -4.0f);
            val = expf(-0.5f * tau * tau) * cosf(5.0f * tau) / sqrtf((float)s);
        }
        W[tid] = val;
    }

    // ---- softmax weight (redundant per thread, cheap) ----
    float mx = -1e30f;
    for (int i = 0; i < NS; ++i) mx = fmaxf(mx, sw[i]);
    float ssum = 0.f;
    for (int i = 0; i < NS; ++i) ssum += expf(sw[i] - mx);
    const float wsoft = expf(sw[sidx] - mx) / ssum;

    __syncthreads();

    const int F0base = tid * 2 + (32 - s);       // f4 index of window start
    float e = 0.f;

    for (int pass = 0; pass < NPASS; ++pass) {
        const int F0 = pass * 512 + F0base;

        float xr[16];
        {
            float4 a = X4[swz(F0 + 0)], b = X4[swz(F0 + 1)];
            float4 c = X4[swz(F0 + 2)], d = X4[swz(F0 + 3)];
            xr[0]=a.x; xr[1]=a.y; xr[2]=a.z; xr[3]=a.w;
            xr[4]=b.x; xr[5]=b.y; xr[6]=b.z; xr[7]=b.w;
            xr[8]=c.x; xr[9]=c.y; xr[10]=c.z; xr[11]=c.w;
            xr[12]=d.x; xr[13]=d.y; xr[14]=d.z; xr[15]=d.w;
        }

        float acc[G];
#pragma unroll
        for (int r = 0; r < G; ++r) acc[r] = 0.f;

        for (int c2 = 0; c2 < nc2; ++c2) {
            const int u0 = c2 * 16;
            // 16 wavelet taps (broadcast reads)
            float wr[16];
            {
                float4 w0 = *reinterpret_cast<const float4*>(&W[u0]);
                float4 w1 = *reinterpret_cast<const float4*>(&W[u0 + 4]);
                float4 w2 = *reinterpret_cast<const float4*>(&W[u0 + 8]);
                float4 w3 = *reinterpret_cast<const float4*>(&W[u0 + 12]);
                wr[0]=w0.x; wr[1]=w0.y; wr[2]=w0.z; wr[3]=w0.w;
                wr[4]=w1.x; wr[5]=w1.y; wr[6]=w1.z; wr[7]=w1.w;
                wr[8]=w2.x; wr[9]=w2.y; wr[10]=w2.z; wr[11]=w2.w;
                wr[12]=w3.x; wr[13]=w3.y; wr[14]=w3.z; wr[15]=w3.w;
            }

            // prefetch refill for chunk A
            float4 pa = X4[swz(F0 + c2 * 4 + 4)];
            float4 pb = X4[swz(F0 + c2 * 4 + 5)];

            // chunk A: taps u0+j, window floats xr[j+r] (j+r <= 14)
#pragma unroll
            for (int j = 0; j < 8; ++j)
#pragma unroll
                for (int r = 0; r < G; ++r)
                    acc[r] = fmaf(wr[j], xr[j + r], acc[r]);

            xr[0]=pa.x; xr[1]=pa.y; xr[2]=pa.z; xr[3]=pa.w;
            xr[4]=pb.x; xr[5]=pb.y; xr[6]=pb.z; xr[7]=pb.w;

            // prefetch refill for chunk B
            float4 pc = X4[swz(F0 + c2 * 4 + 6)];
            float4 pd = X4[swz(F0 + c2 * 4 + 7)];

            // chunk B: taps u0+8+j, window floats xr[(8+j+r)&15]
#pragma unroll
            for (int j = 0; j < 8; ++j)
#pragma unroll
                for (int r = 0; r < G; ++r)
                    acc[r] = fmaf(wr[8 + j], xr[(8 + j + r) & 15], acc[r]);

            xr[8]=pc.x; xr[9]=pc.y; xr[10]=pc.z; xr[11]=pc.w;
            xr[12]=pd.x; xr[13]=pd.y; xr[14]=pd.z; xr[15]=pd.w;
        }

#pragma unroll
        for (int r = 0; r < G; ++r) e = fmaf(acc[r], acc[r], e);
    }

    // ---- block reduction of sum(coef^2) ----
#pragma unroll
    for (int off = 32; off > 0; off >>= 1) e += __shfl_down(e, off);
    if ((tid & 63) == 0) red[tid >> 6] = e;
    __syncthreads();
    if (tid == 0) {
        float tot = red[0] + red[1] + red[2] + red[3];
        out[batch * NS + sidx] = tot * (1.0f / (float)NT) * wsoft;
    }
}

extern "C" void kernel_launch(void* const* d_in, const int* in_sizes, int n_in,
                              void* d_out, int out_size, void* d_ws, size_t ws_size,
                              hipStream_t stream) {
    const float* x  = (const float*)d_in[0];
    const float* sw = (const float*)d_in[1];
    float* out = (float*)d_out;
    const int batch = in_sizes[0] / NT;   // 128
    hipLaunchKernelGGL(cwt_energy_kernel, dim3(batch * NS), dim3(BLOCK), 0, stream,
                       x, sw, out);
}

// Round 3
// 28.235 us; speedup vs baseline: 16.0193x; 5.2248x over previous
//
#include <hip/hip_runtime.h>
#include <hip/hip_bf16.h>
#include <math.h>

// x: [128, 8192] f32, scale_weights: [32] f32, out: [128, 32] f32
// coef[t,s] = sum_{j=0}^{255} bank[j][s] * Xpad[t+j],  Xpad[i] = x[i-128] (zero outside)
// out[b][s] = (sum_t coef^2 / NT) * softmax(sw)[s]
#define NT      8192
#define NS      32
#define KTAPS   256
#define TQ      2048            // t-range per block (4 blocks per row)
#define XELEM   (TQ + KTAPS)    // 2304 Xpad elems needed per block
#define XSTRIDE 2320            // +16 elem pad: copy stride = 1160 words == 8 mod 32 (uniform banks)
#define NCOPY   4

typedef __attribute__((ext_vector_type(8)))  short bf16x8;
typedef __attribute__((ext_vector_type(4)))  short short4v;
typedef __attribute__((ext_vector_type(16))) float f32x16;
typedef __attribute__((ext_vector_type(4)))  float float4v;

// ---------------- kernel 0: bank fragments in exact MFMA A-layout ----------------
// A[s][k] = bank[k][s] = W_s[k - off_s], off_s = 128-4s, L = 8s (W symmetric)
// lane l holds A[m=l&31][k = 16*kap + 8*(l>>5) + j], j=0..7
// layout: abf[kap*512 + l*8 + j]
__global__ void bank_kernel(unsigned short* __restrict__ abf) {
    int e   = blockIdx.x * 256 + threadIdx.x;   // 0..8191
    int kap = e >> 9;
    int l   = (e >> 3) & 63;
    int j   = e & 7;
    int sc  = (l & 31) + 1;                     // scale 1..32
    int k   = kap * 16 + ((l >> 5) << 3) + j;
    int L   = 8 * sc;
    int u   = k - (128 - 4 * sc);
    float val = 0.f;
    if (u >= 0 && u < L) {
        float tau = fmaf(8.0f / (float)(L - 1), (float)u, -4.0f);
        val = expf(-0.5f * tau * tau) * cosf(5.0f * tau) / sqrtf((float)sc);
    }
    __hip_bfloat16 bv = __float2bfloat16(val);
    abf[e] = *reinterpret_cast<unsigned short*>(&bv);
}

// ---------------- kernel 1: main MFMA kernel ----------------
__global__ __launch_bounds__(512, 2)
void cwt_mfma_kernel(const float* __restrict__ x,
                     const unsigned short* __restrict__ abf,
                     float* __restrict__ part)      // [128][4][32]
{
    __shared__ unsigned short XL[NCOPY * XSTRIDE];  // 4 shift-copies of bf16 Xpad slice
    __shared__ float redE[8 * 2 * 16];

    const int tid = threadIdx.x;
    const int b   = blockIdx.x >> 2;
    const int qt  = blockIdx.x & 3;
    const int T0  = qt * TQ;                        // Xpad base index of this block

    // ---- stage: XL[c][i] = bf16(Xpad[T0 + i + c]), i in [0, XELEM) ----
    const float* xrow = x + (size_t)b * NT;
    for (int q = tid; q < XELEM / 4; q += 512) {    // q: aligned 4-elem groups
        float v[8];
        #pragma unroll
        for (int h = 0; h < 2; ++h) {
            int xi = T0 + 4 * (q + h) - 128;        // multiple of 4
            float4v f;
            if (xi >= 0 && xi <= NT - 4) f = *reinterpret_cast<const float4v*>(xrow + xi);
            else { f[0] = 0.f; f[1] = 0.f; f[2] = 0.f; f[3] = 0.f; }
            v[4 * h + 0] = f[0]; v[4 * h + 1] = f[1];
            v[4 * h + 2] = f[2]; v[4 * h + 3] = f[3];
        }
        unsigned short ub[8];
        #pragma unroll
        for (int i = 0; i < 8; ++i) {
            __hip_bfloat16 t = __float2bfloat16(v[i]);
            ub[i] = *reinterpret_cast<unsigned short*>(&t);
        }
        #pragma unroll
        for (int c = 0; c < NCOPY; ++c) {
            short4v w;
            w[0] = (short)ub[c + 0]; w[1] = (short)ub[c + 1];
            w[2] = (short)ub[c + 2]; w[3] = (short)ub[c + 3];
            *reinterpret_cast<short4v*>(&XL[c * XSTRIDE + 4 * q]) = w;
        }
    }
    __syncthreads();

    const int wv   = tid >> 6;                      // wave 0..7: t-macro [256*wv, +256)
    const int lane = tid & 63;
    const int n    = lane & 31;                     // B column (t within tile)
    const int hh   = lane >> 5;                     // k-half

    // B-frag(diag D): lane elem j = Xpad[T0 + 16*D + n + 8*hh + j]
    //   = XL[c=n&3][ 256*wv-is-folded... i0(D) = 256*wv + 16*D + 4*(n>>2) + 8*hh ]
    const unsigned short* xc = &XL[(n & 3) * XSTRIDE];
    const int ibase = 256 * wv + 4 * (n >> 2) + 8 * hh;

    f32x16 zz;
    #pragma unroll
    for (int r = 0; r < 16; ++r) zz[r] = 0.f;
    f32x16 acc[8];
    #pragma unroll
    for (int m = 0; m < 8; ++m) acc[m] = zz;

    bf16x8 ring[16];
    #define LOADB(D) ({                                                              \
        short4v lo_ = *reinterpret_cast<const short4v*>(xc + ibase + 16 * (D));      \
        short4v hi_ = *reinterpret_cast<const short4v*>(xc + ibase + 16 * (D) + 4);  \
        __builtin_shufflevector(lo_, hi_, 0, 1, 2, 3, 4, 5, 6, 7); })

    #pragma unroll
    for (int D = 0; D < 14; ++D) ring[D] = LOADB(D);   // warm diags 0..13

    const unsigned short* ap = abf + lane * 8;
    #pragma unroll
    for (int kap = 0; kap < 16; ++kap) {
        bf16x8 afrag = *reinterpret_cast<const bf16x8*>(ap + kap * 512);
        ring[(kap + 14) & 15] = LOADB(kap + 14);       // steady-state: 1 frag per k-step
        #pragma unroll
        for (int m = 0; m < 8; ++m)
            acc[m] = __builtin_amdgcn_mfma_f32_32x32x16_bf16(
                         afrag, ring[(kap + 2 * m) & 15], acc[m], 0, 0, 0);
    }

    // ---- epilogue: energy partials. C layout: col(t)=lane&31, s=(r&3)+8*(r>>2)+4*hh ----
    float ep[16];
    #pragma unroll
    for (int r = 0; r < 16; ++r) {
        float s = 0.f;
        #pragma unroll
        for (int m = 0; m < 8; ++m) s = fmaf(acc[m][r], acc[m][r], s);
        ep[r] = s;
    }
    #pragma unroll
    for (int r = 0; r < 16; ++r) {
        ep[r] += __shfl_xor(ep[r], 16);
        ep[r] += __shfl_xor(ep[r], 8);
        ep[r] += __shfl_xor(ep[r], 4);
        ep[r] += __shfl_xor(ep[r], 2);
        ep[r] += __shfl_xor(ep[r], 1);
    }
    if ((lane & 31) == 0) {
        #pragma unroll
        for (int r = 0; r < 16; ++r) redE[(wv * 2 + hh) * 16 + r] = ep[r];
    }
    __syncthreads();
    if (tid < 32) {
        int s  = tid;
        int r  = (s >> 3) * 4 + (s & 3);
        int hi = (s >> 2) & 1;
        float tot = 0.f;
        #pragma unroll
        for (int w = 0; w < 8; ++w) tot += redE[(w * 2 + hi) * 16 + r];
        part[(b * 4 + qt) * 32 + s] = tot;
    }
}

// ---------------- kernel 2: combine partials, apply softmax ----------------
__global__ void combine_kernel(const float* __restrict__ part,
                               const float* __restrict__ sw,
                               float* __restrict__ out) {
    int g = blockIdx.x * 256 + threadIdx.x;
    if (g >= 128 * 32) return;
    int b = g >> 5, s = g & 31;
    float mx = -1e30f;
    for (int i = 0; i < NS; ++i) mx = fmaxf(mx, sw[i]);
    float den = 0.f;
    for (int i = 0; i < NS; ++i) den += expf(sw[i] - mx);
    float soft = expf(sw[s] - mx) / den;
    float tot = 0.f;
    #pragma unroll
    for (int qv = 0; qv < 4; ++qv) tot += part[(b * 4 + qv) * 32 + s];
    out[g] = tot * (1.0f / (float)NT) * soft;
}

extern "C" void kernel_launch(void* const* d_in, const int* in_sizes, int n_in,
                              void* d_out, int out_size, void* d_ws, size_t ws_size,
                              hipStream_t stream) {
    const float* x  = (const float*)d_in[0];
    const float* sw = (const float*)d_in[1];
    float* out = (float*)d_out;

    unsigned short* abf = (unsigned short*)d_ws;                 // 16 KB
    float* part = (float*)((char*)d_ws + 16384);                 // 64 KB

    hipLaunchKernelGGL(bank_kernel, dim3(32), dim3(256), 0, stream, abf);
    hipLaunchKernelGGL(cwt_mfma_kernel, dim3(512), dim3(512), 0, stream, x, abf, part);
    hipLaunchKernelGGL(combine_kernel, dim3(16), dim3(256), 0, stream, part, sw, out);
}